// Round 3
// baseline (365.890 us; speedup 1.0000x reference)
//
#include <hip/hip_runtime.h>

// ---------------------------------------------------------------------------
// MSCrossAttnBlock on MI355X (gfx950).
// B=4, E=32, LQ=1024, D=1024, NH=16, DH=64, NP=4. All levels are 32x32.
// R7: ms_sample_fused rewritten as two-phase: phase 1 computes softmax +
//     bilinear weights + packed gather descriptors ONCE per (h,point) (was
//     16x redundant across channel lanes; kernel was VALU-bound at 81%),
//     phase 2 is the gather/accumulate loop reading broadcast LDS tables.
//     Three 4096-row GEMMs moved 64x128 -> 128x128 2-phase (grid 256/320).
//     10 dispatches.
// ---------------------------------------------------------------------------

#define DEV __device__ __forceinline__

typedef float f32x4 __attribute__((ext_vector_type(4)));
typedef __bf16 bf16x8 __attribute__((ext_vector_type(8)));

DEV unsigned short f2bf(float f) {
  union { float f; unsigned u; } a; a.f = f;
  unsigned r = a.u + 0x7fffu + ((a.u >> 16) & 1u);
  return (unsigned short)(r >> 16);
}
DEV float bf2f(unsigned short h) {
  union { unsigned u; float f; } a; a.u = ((unsigned)h) << 16;
  return a.f;
}

// async global -> LDS, 16B per lane; LDS dest = uniform base + lane*16.
DEV void gl_lds16(const unsigned short* g, unsigned short* l) {
  __builtin_amdgcn_global_load_lds(
      (const __attribute__((address_space(1))) void*)g,
      (__attribute__((address_space(3))) void*)l, 16, 0, 0);
}

// ---------------- merged weight fp32 -> bf16 conversion --------------------
struct CvtArgs {
  const float* src[8];
  unsigned short* dst;
  int off4[9];  // prefix sums, float4 units
};

__global__ __launch_bounds__(256) void f2bf_multi(CvtArgs a) {
  int i = blockIdx.x * 256 + threadIdx.x;  // float4 index, exact grid
  int seg = 0;
  #pragma unroll
  for (int s = 1; s < 8; ++s) seg += (i >= a.off4[s]) ? 1 : 0;
  const float4 v = ((const float4*)a.src[seg])[i - a.off4[seg]];
  unsigned short* o = a.dst + (size_t)i * 4;
  o[0] = f2bf(v.x); o[1] = f2bf(v.y); o[2] = f2bf(v.z); o[3] = f2bf(v.w);
}

// ---------------- LayerNorm: one WAVE per row (no barriers, no LDS) --------
DEV void ln_row_wave(const float* __restrict__ xr, const float* __restrict__ g,
                     const float* __restrict__ b,
                     unsigned short* __restrict__ op_row) {
  const int lane = threadIdx.x & 63;
  float4 v[4];
  float s = 0.f, s2 = 0.f;
  #pragma unroll
  for (int j = 0; j < 4; ++j) {
    v[j] = ((const float4*)xr)[lane + 64 * j];
    s  += v[j].x + v[j].y + v[j].z + v[j].w;
    s2 += v[j].x*v[j].x + v[j].y*v[j].y + v[j].z*v[j].z + v[j].w*v[j].w;
  }
  #pragma unroll
  for (int o = 32; o; o >>= 1) { s += __shfl_xor(s, o); s2 += __shfl_xor(s2, o); }
  const float mean = s * (1.f / 1024.f);
  const float rstd = rsqrtf(s2 * (1.f / 1024.f) - mean * mean + 1e-6f);
  #pragma unroll
  for (int j = 0; j < 4; ++j) {
    float4 gg = ((const float4*)g)[lane + 64 * j];
    float4 bb = ((const float4*)b)[lane + 64 * j];
    ushort4 r;
    r.x = f2bf((v[j].x - mean) * rstd * gg.x + bb.x);
    r.y = f2bf((v[j].y - mean) * rstd * gg.y + bb.y);
    r.z = f2bf((v[j].z - mean) * rstd * gg.z + bb.z);
    r.w = f2bf((v[j].w - mean) * rstd * gg.w + bb.w);
    ((ushort4*)op_row)[lane + 64 * j] = r;
  }
}

__global__ __launch_bounds__(256) void ln_wave_kernel(
    const float* __restrict__ x, const float* __restrict__ g,
    const float* __restrict__ b, unsigned short* __restrict__ out) {
  int row = blockIdx.x * 4 + (threadIdx.x >> 6);
  ln_row_wave(x + (size_t)row * 1024, g, b, out + (size_t)row * 1024);
}

// rows 0..16383: feat levels -> f_ln (B,4,1024,1024); rows 16384..20479: q_ln.
__global__ __launch_bounds__(256) void ln5_wave_kernel(
    const float* __restrict__ s0, const float* __restrict__ s1,
    const float* __restrict__ s2, const float* __restrict__ s3,
    const float* __restrict__ fg, const float* __restrict__ fb,
    const float* __restrict__ qg, const float* __restrict__ qb,
    unsigned short* __restrict__ f_out, unsigned short* __restrict__ q_out) {
  int row = blockIdx.x * 4 + (threadIdx.x >> 6);  // 0..20479
  if (row < 16384) {
    int l = row >> 12, inner = row & 4095;
    const float* srcs[4] = {s0, s1, s2, s3};
    int orow = (inner >> 10) * 4096 + l * 1024 + (inner & 1023);
    ln_row_wave(srcs[l] + (size_t)inner * 1024, fg, fb,
                f_out + (size_t)orow * 1024);
  } else {
    int inner = row - 16384;
    ln_row_wave(s3 + (size_t)inner * 1024, qg, qb,
                q_out + (size_t)inner * 1024);
  }
}

// ---------------- shared GEMM param block ----------------------------------
struct GemmP {
  const unsigned short* A; const unsigned short* W;
  void* C; void* C1; void* C2;
  const float* b0; const float* b1; const float* b2;
  const float* src3; const float* g1; const float* g2; const float* attnp;
  int M, N, K, tilesM;
};

// ---------------- 128^2-class bf16 MFMA GEMM (R5 2-phase dbuf) -------------
// EPI: 0=f32, 1=bf16, 2=CA split(off512|attw256), 3=SA split(val1024 bf16|
//      off128 f32|attw64 f32), 4=final combine -> d_out.
template <int BM, int BN, int EPI>
DEV void gemm_body(const GemmP& P, int id, unsigned short* smem) {
  constexpr int WMT = BM / 2, WNT = BN / 2;
  constexpr int MF = WMT / 16, NF = WNT / 16;
  constexpr int PA = BM / 64, PB = BN / 64;    // granule passes per sub-tile
  constexpr int BUF = (BM + BN) * 64;          // elements per LDS buffer
  const int tid = threadIdx.x;
  const int wave = tid >> 6, lane = tid & 63;
  const int wm = (wave & 1) * WMT, wn = (wave >> 1) * WNT;
  const int m0 = (id % P.tilesM) * BM;
  const int n0 = (id / P.tilesM) * BN;
  const int lq = lane >> 4, lm = lane & 15;
  const int r16 = lane >> 2;                    // row within granule
  const int cst = lane & 3;                     // slot within row
  const int csrc = cst ^ ((r16 >> 1) & 3);      // global k-chunk for slot
  const int aslot = lq ^ ((lm >> 1) & 3);       // read slot for chunk lq

  f32x4 acc[MF][NF] = {};
  const int kTiles = P.K >> 6;

  const unsigned short* gA[PA];
  #pragma unroll
  for (int p = 0; p < PA; ++p) {
    int grow = m0 + (wave + 4 * p) * 16 + r16;
    gA[p] = P.A + (size_t)grow * P.K + csrc * 8;
  }
  const unsigned short* gB[PB];
  #pragma unroll
  for (int p = 0; p < PB; ++p) {
    int grow = min(n0 + (wave + 4 * p) * 16 + r16, P.N - 1);
    gB[p] = P.W + (size_t)grow * P.K + csrc * 8;
  }

  auto stage = [&](int b, int t) {
    unsigned short* bA = smem + b * BUF;
    unsigned short* bB = bA + BM * 64;
    const int k0 = t << 6;
    #pragma unroll
    for (int s = 0; s < 2; ++s) {
      #pragma unroll
      for (int p = 0; p < PA; ++p)
        gl_lds16(gA[p] + k0 + s * 32,
                 bA + s * BM * 32 + (wave + 4 * p) * 512);
      #pragma unroll
      for (int p = 0; p < PB; ++p)
        gl_lds16(gB[p] + k0 + s * 32,
                 bB + s * BN * 32 + (wave + 4 * p) * 512);
    }
  };

  stage(0, 0);
  __syncthreads();                 // vmcnt(0) drain: buf0 ready
  int cur = 0;
  #pragma unroll 1
  for (int t = 0; t < kTiles; ++t) {
    if (t + 1 < kTiles) stage(cur ^ 1, t + 1);  // async issue, no wait yet
    const unsigned short* bA = smem + cur * BUF;
    const unsigned short* bB = bA + BM * 64;
    #pragma unroll
    for (int s = 0; s < 2; ++s) {
      bf16x8 af[MF], bfr[NF];
      #pragma unroll
      for (int mi = 0; mi < MF; ++mi)
        af[mi] = *(const bf16x8*)(bA + s * BM * 32 + ((wm >> 4) + mi) * 512 + lm * 32 + aslot * 8);
      #pragma unroll
      for (int ni = 0; ni < NF; ++ni)
        bfr[ni] = *(const bf16x8*)(bB + s * BN * 32 + ((wn >> 4) + ni) * 512 + lm * 32 + aslot * 8);
      #pragma unroll
      for (int mi = 0; mi < MF; ++mi)
        #pragma unroll
        for (int ni = 0; ni < NF; ++ni)
          acc[mi][ni] = __builtin_amdgcn_mfma_f32_16x16x32_bf16(
              af[mi], bfr[ni], acc[mi][ni], 0, 0, 0);
    }
    __syncthreads();   // drains this iter's stage (after MFMA) + barrier
    cur ^= 1;
  }

  #pragma unroll
  for (int mi = 0; mi < MF; ++mi) {
    #pragma unroll
    for (int ni = 0; ni < NF; ++ni) {
      const int col = n0 + wn + ni * 16 + lm;
      #pragma unroll
      for (int r2 = 0; r2 < 4; ++r2) {
        const int row = m0 + wm + mi * 16 + lq * 4 + r2;
        float v = acc[mi][ni][r2];
        if constexpr (EPI == 0) {
          ((float*)P.C)[(size_t)row * 1024 + col] = v + P.b0[col];
        } else if constexpr (EPI == 1) {
          ((unsigned short*)P.C)[(size_t)row * 1024 + col] = f2bf(v + P.b0[col]);
        } else if constexpr (EPI == 2) {
          if (col < 512)
            ((float*)P.C)[(size_t)row * 512 + col] = v + P.b0[col];
          else
            ((float*)P.C1)[(size_t)row * 256 + col - 512] = v + P.b1[col - 512];
        } else if constexpr (EPI == 3) {
          if (col < 1024)
            ((unsigned short*)P.C)[(size_t)row * 1024 + col] = f2bf(v + P.b0[col]);
          else if (col < 1152)
            ((float*)P.C1)[(size_t)row * 128 + col - 1024] = v + P.b1[col - 1024];
          else if (col < 1216)
            ((float*)P.C2)[(size_t)row * 64 + col - 1152] = v + P.b2[col - 1152];
        } else {  // EPI == 4: out = src3 + g1*(attn + g2*(v+b))
          size_t i = (size_t)row * 1024 + col;
          float vv = v + P.b0[col];
          ((float*)P.C)[i] = P.src3[i] + P.g1[col] * (P.attnp[i] + P.g2[col] * vv);
        }
      }
    }
  }
}

template <int BM, int BN, int EPI>
__global__ __launch_bounds__(256) void gemm_v3(GemmP P) {
  extern __shared__ __align__(16) unsigned short smem[];
  gemm_body<BM, BN, EPI>(P, blockIdx.x, smem);
}

// ---------------- 256^2 8-wave 4-phase counted-vmcnt GEMM (CA value) -------
// See R6 comment block: T3+T4+T5, region schedule from quadrant death
// analysis, vmcnt(8) uniform, epilogue staging clamped to kT-1.
__global__ __launch_bounds__(512, 2) void gemm256(GemmP P) {
  __shared__ __align__(16) unsigned short smem[65536];  // 128KB
  const int tid = threadIdx.x;
  const int wave = tid >> 6, lane = tid & 63;
  const int wm = (wave & 1) * 128, wn = (wave >> 1) * 64;
  const int m0 = (blockIdx.x & 63) * 256;   // n-major id: A panel stays on XCD
  const int n0 = (blockIdx.x >> 6) * 256;
  const int lq = lane >> 4, lm = lane & 15;
  const int r16 = lane >> 2, cst = lane & 3;
  const int csrc = cst ^ ((r16 >> 1) & 3);
  const int aslot = lq ^ ((lm >> 1) & 3);
  const int K = P.K;
  const int kT = K >> 6;                     // 16

  const int gA0 = (wave & 3) + ((wave >> 2) << 3);   // R0: {0..3,8..11}
  const int gB2 = ((wave >> 1) << 2) + (wave & 1);   // R2: {0,1,4,5,8,9,12,13}
  const unsigned short* baseA0 =
      P.A + (size_t)(m0 + gA0 * 16 + r16) * K + csrc * 8;
  const unsigned short* baseA1 = baseA0 + (size_t)64 * K;   // R1 = R0 + 4 granules
  const unsigned short* baseB2 =
      P.W + (size_t)(n0 + gB2 * 16 + r16) * K + csrc * 8;
  const unsigned short* baseB3 = baseB2 + (size_t)32 * K;   // R3 = R2 + 2 granules
  const int ldsA0 = gA0 * 512 + lane * 8;
  const int ldsA1 = (gA0 + 4) * 512 + lane * 8;
  const int ldsB2 = 16384 + gB2 * 512 + lane * 8;
  const int ldsB3 = 16384 + (gB2 + 2) * 512 + lane * 8;

  auto stg = [&](const unsigned short* gbase, int ldsOff, int buf, int tsrc) {
    const unsigned short* g = gbase + tsrc * 64;
    unsigned short* l = smem + buf * 32768 + ldsOff;
    gl_lds16(g, l);               // s = 0
    gl_lds16(g + 32, l + 8192);   // s = 1
  };

  const int aBase = (wave & 1) * 8;    // A read granule base
  const int bBase = (wave >> 1) * 4;   // B read granule base
  const int rdI = lm * 32 + aslot * 8;

  auto rdA = [&](int buf, int s, int gi) {
    return *(const bf16x8*)(smem + buf * 32768 + s * 8192 + (aBase + gi) * 512 + rdI);
  };
  auto rdB = [&](int buf, int s, int gi) {
    return *(const bf16x8*)(smem + buf * 32768 + 16384 + s * 8192 + (bBase + gi) * 512 + rdI);
  };

  f32x4 acc[8][4] = {};
  bf16x8 a[2][4], b0[2][2], b1[2][2];

#define VMB8() asm volatile("s_waitcnt vmcnt(8)\ns_barrier" ::: "memory")

  stg(baseA0, ldsA0, 0, 0);
  stg(baseB2, ldsB2, 0, 0);
  stg(baseB3, ldsB3, 0, 0);
  stg(baseA1, ldsA1, 0, 0);
  stg(baseA0, ldsA0, 1, min(1, kT - 1));
  stg(baseB2, ldsB2, 1, min(1, kT - 1));

  auto iterate = [&](int t, int c) {
    const int nc = c ^ 1;
    const int t1 = min(t + 1, kT - 1);
    const int t2 = min(t + 2, kT - 1);
    // ---- p0: (qm0,qn0) ----
    VMB8();
    stg(baseB3, ldsB3, nc, t1);
    #pragma unroll
    for (int s = 0; s < 2; ++s) {
      #pragma unroll
      for (int i = 0; i < 4; ++i) a[s][i] = rdA(c, s, i);
      #pragma unroll
      for (int i = 0; i < 2; ++i) b0[s][i] = rdB(c, s, i);
    }
    __builtin_amdgcn_s_setprio(1);
    #pragma unroll
    for (int s = 0; s < 2; ++s)
      #pragma unroll
      for (int mi = 0; mi < 4; ++mi)
        #pragma unroll
        for (int ni = 0; ni < 2; ++ni)
          acc[mi][ni] = __builtin_amdgcn_mfma_f32_16x16x32_bf16(
              a[s][mi], b0[s][ni], acc[mi][ni], 0, 0, 0);
    __builtin_amdgcn_s_setprio(0);
    // ---- p1: (qm0,qn1) ----
    VMB8();
    stg(baseA1, ldsA1, nc, t1);
    #pragma unroll
    for (int s = 0; s < 2; ++s)
      #pragma unroll
      for (int i = 0; i < 2; ++i) b1[s][i] = rdB(c, s, 2 + i);
    __builtin_amdgcn_s_setprio(1);
    #pragma unroll
    for (int s = 0; s < 2; ++s)
      #pragma unroll
      for (int mi = 0; mi < 4; ++mi)
        #pragma unroll
        for (int ni = 0; ni < 2; ++ni)
          acc[mi][2 + ni] = __builtin_amdgcn_mfma_f32_16x16x32_bf16(
              a[s][mi], b1[s][ni], acc[mi][2 + ni], 0, 0, 0);
    __builtin_amdgcn_s_setprio(0);
    // ---- p2: (qm1,qn0) ----
    VMB8();
    stg(baseA0, ldsA0, c, t2);
    #pragma unroll
    for (int s = 0; s < 2; ++s)
      #pragma unroll
      for (int i = 0; i < 4; ++i) a[s][i] = rdA(c, s, 4 + i);
    __builtin_amdgcn_s_setprio(1);
    #pragma unroll
    for (int s = 0; s < 2; ++s)
      #pragma unroll
      for (int mi = 0; mi < 4; ++mi)
        #pragma unroll
        for (int ni = 0; ni < 2; ++ni)
          acc[4 + mi][ni] = __builtin_amdgcn_mfma_f32_16x16x32_bf16(
              a[s][mi], b0[s][ni], acc[4 + mi][ni], 0, 0, 0);
    __builtin_amdgcn_s_setprio(0);
    // ---- p3: (qm1,qn1) ----
    VMB8();
    stg(baseB2, ldsB2, c, t2);
    __builtin_amdgcn_s_setprio(1);
    #pragma unroll
    for (int s = 0; s < 2; ++s)
      #pragma unroll
      for (int mi = 0; mi < 4; ++mi)
        #pragma unroll
        for (int ni = 0; ni < 2; ++ni)
          acc[4 + mi][2 + ni] = __builtin_amdgcn_mfma_f32_16x16x32_bf16(
              a[s][mi], b1[s][ni], acc[4 + mi][2 + ni], 0, 0, 0);
    __builtin_amdgcn_s_setprio(0);
  };

  #pragma unroll 1
  for (int t = 0; t < kT; t += 2) {
    iterate(t, 0);
    iterate(t + 1, 1);
  }
  asm volatile("s_waitcnt vmcnt(0)" ::: "memory");
#undef VMB8

  #pragma unroll
  for (int mi = 0; mi < 8; ++mi) {
    #pragma unroll
    for (int ni = 0; ni < 4; ++ni) {
      const int col = n0 + wn + ni * 16 + lm;
      #pragma unroll
      for (int r2 = 0; r2 < 4; ++r2) {
        const int row = m0 + wm + mi * 16 + lq * 4 + r2;
        ((unsigned short*)P.C)[(size_t)row * 1024 + col] =
            f2bf(acc[mi][ni][r2] + P.b0[col]);
      }
    }
  }
}

// ---------------- fused softmax + MS-deform bilinear sampling --------------
// Two-phase: phase 1 = one thread per (head,point) computes softmax weight,
// bilinear corner weights (validity+aw folded) and a packed gather
// descriptor into bank-padded LDS tables. Phase 2 = channel lanes gather
// 4 corners per point and accumulate; per-point VALU drops ~2x vs R6
// (weight math was replicated across all 16 channel lanes; VALUBusy 81%).
template <int NLEV>
__global__ __launch_bounds__(256) void ms_sample_fused(
    const unsigned short* __restrict__ value, const float* __restrict__ off,
    const float* __restrict__ logits, unsigned short* __restrict__ out) {
  constexpr int NPTS = NLEV * 4;
  constexpr int STR = NPTS + 1;  // LDS row pad: h-groups hit distinct banks
  __shared__ float4 wTab[16 * STR];
  __shared__ int2  iTab[16 * STR];
  const int nq = blockIdx.x;               // n*1024 + q
  const int tid = threadIdx.x;
  const int q = nq & 1023, n = nq >> 10;

  if (tid < 16 * NPTS) {
    const int h1 = tid / NPTS;             // NPTS power of 2 -> shift
    const int p1 = tid - h1 * NPTS;        // point index (l*4+p)
    float lg = logits[((size_t)nq * 16 + h1) * NPTS + p1];
    float mx = lg;
    #pragma unroll
    for (int m = 1; m < NPTS; m <<= 1) mx = fmaxf(mx, __shfl_xor(mx, m));
    const float e = __expf(lg - mx);
    float sum = e;
    #pragma unroll
    for (int m = 1; m < NPTS; m <<= 1) sum += __shfl_xor(sum, m);
    const float aw = e / sum;
    const float2 o2 =
        ((const float2*)(off + ((size_t)nq * 16 + h1) * NPTS * 2))[p1];
    const float fqx = (float)(q & 31), fqy = (float)(q >> 5);
    float xx = fqx + o2.x, yy = fqy + o2.y;
    float xf = floorf(xx), yf = floorf(yy);
    float fx = xx - xf, fy = yy - yf;
    int ix = (int)xf, iy = (int)yf;
    int ix1 = ix + 1, iy1 = iy + 1;
    float vx0 = ((unsigned)ix  < 32u) ? 1.f : 0.f;
    float vx1 = ((unsigned)ix1 < 32u) ? 1.f : 0.f;
    float vy0 = ((unsigned)iy  < 32u) ? 1.f : 0.f;
    float vy1 = ((unsigned)iy1 < 32u) ? 1.f : 0.f;
    int cx0 = min(max(ix, 0), 31), cx1 = min(max(ix1, 0), 31);
    int cy0 = min(max(iy, 0), 31), cy1 = min(max(iy1, 0), 31);
    float4 w;
    w.x = (1.f - fx) * (1.f - fy) * vx0 * vy0 * aw;
    w.y = fx * (1.f - fy) * vx1 * vy0 * aw;
    w.z = (1.f - fx) * fy * vx0 * vy1 * aw;
    w.w = fx * fy * vx1 * vy1 * aw;
    const int l = p1 >> 2;
    int2 io;
    io.x = ((n * NLEV + l) << 20) + ((cy0 * 32 + cx0) << 10);  // element off
    io.y = (cx1 - cx0) | ((cy1 - cy0) << 1);                   // dx | dy<<1
    wTab[h1 * STR + p1] = w;
    iTab[h1 * STR + p1] = io;
  }
  __syncthreads();

  const int wave = tid >> 6, lane = tid & 63;
  const int h = (wave << 2) + (lane >> 4);
  const int c = (lane & 15) << 2;          // channel base (0..60)
  const unsigned short* __restrict__ vb = value + h * 64 + c;
  float a0 = 0.f, a1 = 0.f, a2 = 0.f, a3 = 0.f;

  #pragma unroll 4
  for (int p = 0; p < NPTS; ++p) {
    const float4 w = wTab[h * STR + p];    // broadcast within 16-lane group
    const int2 io = iTab[h * STR + p];
    const unsigned short* b = vb + io.x;
    const int sx = (io.y & 1) << 10;       // +1 position = 1024 elements
    const int sy = (io.y & 2) << 14;       // +1 row = 32768 elements
    ushort4 u00 = *(const ushort4*)(b);
    ushort4 u01 = *(const ushort4*)(b + sx);
    ushort4 u10 = *(const ushort4*)(b + sy);
    ushort4 u11 = *(const ushort4*)(b + sx + sy);
    a0 += w.x * bf2f(u00.x) + w.y * bf2f(u01.x) + w.z * bf2f(u10.x) + w.w * bf2f(u11.x);
    a1 += w.x * bf2f(u00.y) + w.y * bf2f(u01.y) + w.z * bf2f(u10.y) + w.w * bf2f(u11.y);
    a2 += w.x * bf2f(u00.z) + w.y * bf2f(u01.z) + w.z * bf2f(u10.z) + w.w * bf2f(u11.z);
    a3 += w.x * bf2f(u00.w) + w.y * bf2f(u01.w) + w.z * bf2f(u10.w) + w.w * bf2f(u11.w);
  }
  ushort4 r;
  r.x = f2bf(a0); r.y = f2bf(a1); r.z = f2bf(a2); r.w = f2bf(a3);
  *(ushort4*)(out + ((size_t)nq * 16 + h) * 64 + c) = r;
}

// ---------------------------------------------------------------------------
extern "C" void kernel_launch(void* const* d_in, const int* in_sizes, int n_in,
                              void* d_out, int out_size, void* d_ws,
                              size_t ws_size, hipStream_t stream) {
  (void)in_sizes; (void)n_in; (void)out_size; (void)ws_size;
  const float* src[4] = {(const float*)d_in[0], (const float*)d_in[1],
                         (const float*)d_in[2], (const float*)d_in[3]};
  const float* qn_g = (const float*)d_in[4];
  const float* qn_b = (const float*)d_in[5];
  const float* fn_g = (const float*)d_in[6];
  const float* fn_b = (const float*)d_in[7];
  const float* n1_g = (const float*)d_in[8];
  const float* n1_b = (const float*)d_in[9];
  const float* gamma1 = (const float*)d_in[10];
  const float* gamma2 = (const float*)d_in[11];
  const float* ca_vw = (const float*)d_in[12];
  const float* ca_vb = (const float*)d_in[13];
  const float* ca_ow = (const float*)d_in[14];
  const float* ca_ob = (const float*)d_in[15];
  const float* ca_aw = (const float*)d_in[16];
  const float* ca_ab = (const float*)d_in[17];
  const float* ca_pw = (const float*)d_in[18];
  const float* ca_pb = (const float*)d_in[19];
  const float* sa_vw = (const float*)d_in[20];
  const float* sa_vb = (const float*)d_in[21];
  const float* sa_ow = (const float*)d_in[22];
  const float* sa_ob = (const float*)d_in[23];
  const float* sa_aw = (const float*)d_in[24];
  const float* sa_ab = (const float*)d_in[25];
  const float* sa_pw = (const float*)d_in[26];
  const float* sa_pb = (const float*)d_in[27];

  // ---- workspace layout ----
  char* wsp = (char*)d_ws;
  size_t off = 0;
  auto alloc = [&](size_t bytes) {
    char* r = wsp + off;
    off = (off + bytes + 255) & ~(size_t)255;
    return r;
  };
  const size_t MB = 1024 * 1024;
  unsigned short* w_ca_vw = (unsigned short*)alloc(1024 * 1024 * 2);
  unsigned short* w_ca_ow = (unsigned short*)alloc(512 * 1024 * 2);
  unsigned short* w_ca_aw = (unsigned short*)alloc(256 * 1024 * 2);
  unsigned short* w_ca_pw = (unsigned short*)alloc(1024 * 1024 * 2);
  unsigned short* w_sa_vw = (unsigned short*)alloc(1024 * 1024 * 2);
  unsigned short* w_sa_ow = (unsigned short*)alloc(128 * 1024 * 2);
  unsigned short* w_sa_aw = (unsigned short*)alloc(64 * 1024 * 2);
  unsigned short* w_sa_pw = (unsigned short*)alloc(1024 * 1024 * 2);
  (void)w_ca_aw; (void)w_sa_ow; (void)w_sa_aw;
  char* R1 = alloc(32 * MB);  // f_ln bf16 | attn f32 + attn1 bf16 + samp_sa bf16
  char* R2 = alloc(32 * MB);  // val_ca bf16 | val_sa bf16
  char* R3 = alloc(8 * MB);   // q_ln bf16 | samp_ca bf16
  char* R4 = alloc(8 * MB);   // off_ca f32 | off_sa f32 + attw_sa f32
  char* R5 = alloc(4 * MB);   // attw_ca f32 (raw logits; softmax fused)

  unsigned short* f_ln    = (unsigned short*)R1;
  float*          attn    = (float*)R1;
  unsigned short* attn1   = (unsigned short*)(R1 + 16 * MB);
  unsigned short* samp_sa = (unsigned short*)(R1 + 24 * MB);
  unsigned short* val_ca  = (unsigned short*)R2;
  unsigned short* val_sa  = (unsigned short*)R2;
  unsigned short* q_ln    = (unsigned short*)R3;
  unsigned short* samp_ca = (unsigned short*)R3;
  float*          off_ca  = (float*)R4;
  float*          off_sa  = (float*)R4;
  float*          attw_sa = (float*)(R4 + 4 * MB);
  float*          attw_ca = (float*)R5;

  // ---- 1. merged weight conversion ----
  CvtArgs ca;
  ca.src[0] = ca_vw; ca.src[1] = ca_ow; ca.src[2] = ca_aw; ca.src[3] = ca_pw;
  ca.src[4] = sa_vw; ca.src[5] = sa_ow; ca.src[6] = sa_aw; ca.src[7] = sa_pw;
  ca.dst = w_ca_vw;
  const int sizes4[8] = {262144, 131072, 65536, 262144, 262144, 32768, 16384, 262144};
  ca.off4[0] = 0;
  for (int i = 0; i < 8; ++i) ca.off4[i + 1] = ca.off4[i] + sizes4[i];
  f2bf_multi<<<ca.off4[8] / 256, 256, 0, stream>>>(ca);

  // ---- 2. LayerNorms (feat x4 + query; wave per row) ----
  ln5_wave_kernel<<<5120, 256, 0, stream>>>(src[0], src[1], src[2], src[3],
                                            fn_g, fn_b, qn_g, qn_b, f_ln, q_ln);

  auto mkP = [](const unsigned short* A, const unsigned short* W, void* C,
                const float* b0, int M, int N, int K, int tilesM) {
    GemmP p{}; p.A = A; p.W = W; p.C = C; p.b0 = b0;
    p.M = M; p.N = N; p.K = K; p.tilesM = tilesM;
    return p;
  };

  constexpr int LDS_128 = 2 * (128 + 128) * 64 * 2;  // 65536

  // ---- 3. CA: value GEMM (256^2 counted-vmcnt) + off/attw GEMM ----
  gemm256<<<256, 512, 0, stream>>>(
      mkP(f_ln, w_ca_vw, val_ca, ca_vb, 16384, 1024, 1024, 64));
  {
    GemmP po = mkP(q_ln, w_ca_ow, off_ca, ca_ob, 4096, 768, 1024, 32);
    po.C1 = attw_ca; po.b1 = ca_ab;
    gemm_v3<128, 128, 2><<<192, 256, LDS_128, stream>>>(po);
  }

  // ---- 4. CA sampling + projection ----
  ms_sample_fused<4><<<4096, 256, 0, stream>>>(val_ca, off_ca, attw_ca, samp_ca);
  gemm_v3<128, 128, 0><<<256, 256, LDS_128, stream>>>(
      mkP(samp_ca, w_ca_pw, attn, ca_pb, 4096, 1024, 1024, 32));

  // ---- 5. SA branch ----
  ln_wave_kernel<<<1024, 256, 0, stream>>>(attn, n1_g, n1_b, attn1);
  {
    GemmP p = mkP(attn1, w_sa_vw, val_sa, sa_vb, 4096, 1216, 1024, 32);
    p.C1 = off_sa; p.b1 = sa_ob; p.C2 = attw_sa; p.b2 = sa_ab;
    gemm_v3<128, 128, 3><<<320, 256, LDS_128, stream>>>(p);
  }
  ms_sample_fused<1><<<4096, 256, 0, stream>>>(val_sa, off_sa, attw_sa, samp_sa);
  {
    GemmP p = mkP(samp_sa, w_sa_pw, d_out, sa_pb, 4096, 1024, 1024, 32);
    p.src3 = src[3]; p.g1 = gamma1; p.g2 = gamma2; p.attnp = attn;
    gemm_v3<128, 128, 4><<<256, 256, LDS_128, stream>>>(p);
  }
}

// Round 4
// 351.689 us; speedup vs baseline: 1.0404x; 1.0404x over previous
//
#include <hip/hip_runtime.h>

// ---------------------------------------------------------------------------
// MSCrossAttnBlock on MI355X (gfx950).
// B=4, E=32, LQ=1024, D=1024, NH=16, DH=64, NP=4. All levels are 32x32.
// R8: gemm_v3 K-loop upgraded 2-slot/vmcnt(0)-drain -> 3-slot LDS with
//     counted s_waitcnt vmcnt(16): loads age 2 full K-iterations before the
//     wait; barrier never drains VMEM. (R3 diagnosis: ALL GEMMs pinned at
//     ~47us = 16 K-tiles x ~7000cy -> effective load latency ~2000+cy,
//     2-phase drain fully exposed it.) Static 72KB LDS, 2 blocks/CU.
//     Grids: proj/final 512, saval 640, off/attw 384 (64x128 tiles).
//     gemm256 (716 TF) and ms_sample (R7 two-phase) unchanged.
//     10 dispatches.
// ---------------------------------------------------------------------------

#define DEV __device__ __forceinline__

typedef float f32x4 __attribute__((ext_vector_type(4)));
typedef __bf16 bf16x8 __attribute__((ext_vector_type(8)));

DEV unsigned short f2bf(float f) {
  union { float f; unsigned u; } a; a.f = f;
  unsigned r = a.u + 0x7fffu + ((a.u >> 16) & 1u);
  return (unsigned short)(r >> 16);
}
DEV float bf2f(unsigned short h) {
  union { unsigned u; float f; } a; a.u = ((unsigned)h) << 16;
  return a.f;
}

// async global -> LDS, 16B per lane; LDS dest = uniform base + lane*16.
DEV void gl_lds16(const unsigned short* g, unsigned short* l) {
  __builtin_amdgcn_global_load_lds(
      (const __attribute__((address_space(1))) void*)g,
      (__attribute__((address_space(3))) void*)l, 16, 0, 0);
}

// ---------------- merged weight fp32 -> bf16 conversion --------------------
struct CvtArgs {
  const float* src[8];
  unsigned short* dst;
  int off4[9];  // prefix sums, float4 units
};

__global__ __launch_bounds__(256) void f2bf_multi(CvtArgs a) {
  int i = blockIdx.x * 256 + threadIdx.x;  // float4 index, exact grid
  int seg = 0;
  #pragma unroll
  for (int s = 1; s < 8; ++s) seg += (i >= a.off4[s]) ? 1 : 0;
  const float4 v = ((const float4*)a.src[seg])[i - a.off4[seg]];
  unsigned short* o = a.dst + (size_t)i * 4;
  o[0] = f2bf(v.x); o[1] = f2bf(v.y); o[2] = f2bf(v.z); o[3] = f2bf(v.w);
}

// ---------------- LayerNorm: one WAVE per row (no barriers, no LDS) --------
DEV void ln_row_wave(const float* __restrict__ xr, const float* __restrict__ g,
                     const float* __restrict__ b,
                     unsigned short* __restrict__ op_row) {
  const int lane = threadIdx.x & 63;
  float4 v[4];
  float s = 0.f, s2 = 0.f;
  #pragma unroll
  for (int j = 0; j < 4; ++j) {
    v[j] = ((const float4*)xr)[lane + 64 * j];
    s  += v[j].x + v[j].y + v[j].z + v[j].w;
    s2 += v[j].x*v[j].x + v[j].y*v[j].y + v[j].z*v[j].z + v[j].w*v[j].w;
  }
  #pragma unroll
  for (int o = 32; o; o >>= 1) { s += __shfl_xor(s, o); s2 += __shfl_xor(s2, o); }
  const float mean = s * (1.f / 1024.f);
  const float rstd = rsqrtf(s2 * (1.f / 1024.f) - mean * mean + 1e-6f);
  #pragma unroll
  for (int j = 0; j < 4; ++j) {
    float4 gg = ((const float4*)g)[lane + 64 * j];
    float4 bb = ((const float4*)b)[lane + 64 * j];
    ushort4 r;
    r.x = f2bf((v[j].x - mean) * rstd * gg.x + bb.x);
    r.y = f2bf((v[j].y - mean) * rstd * gg.y + bb.y);
    r.z = f2bf((v[j].z - mean) * rstd * gg.z + bb.z);
    r.w = f2bf((v[j].w - mean) * rstd * gg.w + bb.w);
    ((ushort4*)op_row)[lane + 64 * j] = r;
  }
}

__global__ __launch_bounds__(256) void ln_wave_kernel(
    const float* __restrict__ x, const float* __restrict__ g,
    const float* __restrict__ b, unsigned short* __restrict__ out) {
  int row = blockIdx.x * 4 + (threadIdx.x >> 6);
  ln_row_wave(x + (size_t)row * 1024, g, b, out + (size_t)row * 1024);
}

// rows 0..16383: feat levels -> f_ln (B,4,1024,1024); rows 16384..20479: q_ln.
__global__ __launch_bounds__(256) void ln5_wave_kernel(
    const float* __restrict__ s0, const float* __restrict__ s1,
    const float* __restrict__ s2, const float* __restrict__ s3,
    const float* __restrict__ fg, const float* __restrict__ fb,
    const float* __restrict__ qg, const float* __restrict__ qb,
    unsigned short* __restrict__ f_out, unsigned short* __restrict__ q_out) {
  int row = blockIdx.x * 4 + (threadIdx.x >> 6);  // 0..20479
  if (row < 16384) {
    int l = row >> 12, inner = row & 4095;
    const float* srcs[4] = {s0, s1, s2, s3};
    int orow = (inner >> 10) * 4096 + l * 1024 + (inner & 1023);
    ln_row_wave(srcs[l] + (size_t)inner * 1024, fg, fb,
                f_out + (size_t)orow * 1024);
  } else {
    int inner = row - 16384;
    ln_row_wave(s3 + (size_t)inner * 1024, qg, qb,
                q_out + (size_t)inner * 1024);
  }
}

// ---------------- shared GEMM param block ----------------------------------
struct GemmP {
  const unsigned short* A; const unsigned short* W;
  void* C; void* C1; void* C2;
  const float* b0; const float* b1; const float* b2;
  const float* src3; const float* g1; const float* g2; const float* attnp;
  int M, N, K, tilesM;
};

// ---------------- bf16 MFMA GEMM, 3-slot LDS + counted vmcnt(16) -----------
// C[M,N] = A[M,K] @ W[N,K]^T (+bias). BK=64 as two 32-k sub-tiles.
// Per K-tile t: {s_barrier; stage tile t+2 -> slot (t+2)%3; vmcnt(16)
// (waits only tile t's 8 loads, issued 2 iterations ago); ds_read slot
// t%3; MFMA}. Slot written at t was last read at t-1 (barrier-protected);
// tail stages clamp to kT-1 (dead idempotent writes, uniform vmcnt).
// EPI: 0=f32, 1=bf16, 2=CA split(off512|attw256), 3=SA split(val1024 bf16|
//      off128 f32|attw64 f32), 4=final combine -> d_out.
template <int BM, int BN, int EPI>
DEV void gemm_body(const GemmP& P, int id, unsigned short* smem) {
  constexpr int WMT = BM / 2, WNT = BN / 2;
  constexpr int MF = WMT / 16, NF = WNT / 16;
  constexpr int PA = BM / 64, PB = BN / 64;    // granule passes per sub-tile
  constexpr int BUF = (BM + BN) * 64;          // elements per LDS slot
  const int tid = threadIdx.x;
  const int wave = tid >> 6, lane = tid & 63;
  const int wm = (wave & 1) * WMT, wn = (wave >> 1) * WNT;
  const int m0 = (id % P.tilesM) * BM;
  const int n0 = (id / P.tilesM) * BN;
  const int lq = lane >> 4, lm = lane & 15;
  const int r16 = lane >> 2;                    // row within granule
  const int cst = lane & 3;                     // slot within row
  const int csrc = cst ^ ((r16 >> 1) & 3);      // global k-chunk for slot
  const int aslot = lq ^ ((lm >> 1) & 3);       // read slot for chunk lq

  f32x4 acc[MF][NF] = {};
  const int kTiles = P.K >> 6;

  const unsigned short* gA[PA];
  #pragma unroll
  for (int p = 0; p < PA; ++p) {
    int grow = m0 + (wave + 4 * p) * 16 + r16;
    gA[p] = P.A + (size_t)grow * P.K + csrc * 8;
  }
  const unsigned short* gB[PB];
  #pragma unroll
  for (int p = 0; p < PB; ++p) {
    int grow = min(n0 + (wave + 4 * p) * 16 + r16, P.N - 1);
    gB[p] = P.W + (size_t)grow * P.K + csrc * 8;
  }

  auto stage = [&](int sl, int t) {
    unsigned short* bA = smem + sl * BUF;
    unsigned short* bB = bA + BM * 64;
    const int k0 = t << 6;
    #pragma unroll
    for (int s = 0; s < 2; ++s) {
      #pragma unroll
      for (int p = 0; p < PA; ++p)
        gl_lds16(gA[p] + k0 + s * 32,
                 bA + s * BM * 32 + (wave + 4 * p) * 512);
      #pragma unroll
      for (int p = 0; p < PB; ++p)
        gl_lds16(gB[p] + k0 + s * 32,
                 bB + s * BN * 32 + (wave + 4 * p) * 512);
    }
  };

  // prologue: tiles 0 and 1 in flight (16 loads/wave outstanding)
  stage(0, 0);
  stage(1, min(1, kTiles - 1));
  int sl0 = 0, sl1 = 1, sl2 = 2;
  #pragma unroll 1
  for (int t = 0; t < kTiles; ++t) {
    __builtin_amdgcn_s_barrier();            // prior iter's reads all done
    stage(sl2, min(t + 2, kTiles - 1));      // async issue, no wait
    asm volatile("s_waitcnt vmcnt(16)" ::: "memory");  // tile t landed
    const unsigned short* bA = smem + sl0 * BUF;
    const unsigned short* bB = bA + BM * 64;
    #pragma unroll
    for (int s = 0; s < 2; ++s) {
      bf16x8 af[MF], bfr[NF];
      #pragma unroll
      for (int mi = 0; mi < MF; ++mi)
        af[mi] = *(const bf16x8*)(bA + s * BM * 32 + ((wm >> 4) + mi) * 512 + lm * 32 + aslot * 8);
      #pragma unroll
      for (int ni = 0; ni < NF; ++ni)
        bfr[ni] = *(const bf16x8*)(bB + s * BN * 32 + ((wn >> 4) + ni) * 512 + lm * 32 + aslot * 8);
      #pragma unroll
      for (int mi = 0; mi < MF; ++mi)
        #pragma unroll
        for (int ni = 0; ni < NF; ++ni)
          acc[mi][ni] = __builtin_amdgcn_mfma_f32_16x16x32_bf16(
              af[mi], bfr[ni], acc[mi][ni], 0, 0, 0);
    }
    int tmp = sl0; sl0 = sl1; sl1 = sl2; sl2 = tmp;  // rotate slots
  }
  asm volatile("s_waitcnt vmcnt(0)" ::: "memory");   // drain tail stages

  #pragma unroll
  for (int mi = 0; mi < MF; ++mi) {
    #pragma unroll
    for (int ni = 0; ni < NF; ++ni) {
      const int col = n0 + wn + ni * 16 + lm;
      #pragma unroll
      for (int r2 = 0; r2 < 4; ++r2) {
        const int row = m0 + wm + mi * 16 + lq * 4 + r2;
        float v = acc[mi][ni][r2];
        if constexpr (EPI == 0) {
          ((float*)P.C)[(size_t)row * 1024 + col] = v + P.b0[col];
        } else if constexpr (EPI == 1) {
          ((unsigned short*)P.C)[(size_t)row * 1024 + col] = f2bf(v + P.b0[col]);
        } else if constexpr (EPI == 2) {
          if (col < 512)
            ((float*)P.C)[(size_t)row * 512 + col] = v + P.b0[col];
          else
            ((float*)P.C1)[(size_t)row * 256 + col - 512] = v + P.b1[col - 512];
        } else if constexpr (EPI == 3) {
          if (col < 1024)
            ((unsigned short*)P.C)[(size_t)row * 1024 + col] = f2bf(v + P.b0[col]);
          else if (col < 1152)
            ((float*)P.C1)[(size_t)row * 128 + col - 1024] = v + P.b1[col - 1024];
          else if (col < 1216)
            ((float*)P.C2)[(size_t)row * 64 + col - 1152] = v + P.b2[col - 1152];
        } else {  // EPI == 4: out = src3 + g1*(attn + g2*(v+b))
          size_t i = (size_t)row * 1024 + col;
          float vv = v + P.b0[col];
          ((float*)P.C)[i] = P.src3[i] + P.g1[col] * (P.attnp[i] + P.g2[col] * vv);
        }
      }
    }
  }
}

template <int BM, int BN, int EPI>
__global__ __launch_bounds__(256) void gemm_v3(GemmP P) {
  __shared__ __align__(16) unsigned short smem[3 * (BM + BN) * 64];
  gemm_body<BM, BN, EPI>(P, blockIdx.x, smem);
}

// ---------------- 256^2 8-wave 4-phase counted-vmcnt GEMM (CA value) -------
// See R6 comment block: T3+T4+T5, region schedule from quadrant death
// analysis, vmcnt(8) uniform, epilogue staging clamped to kT-1.
__global__ __launch_bounds__(512, 2) void gemm256(GemmP P) {
  __shared__ __align__(16) unsigned short smem[65536];  // 128KB
  const int tid = threadIdx.x;
  const int wave = tid >> 6, lane = tid & 63;
  const int wm = (wave & 1) * 128, wn = (wave >> 1) * 64;
  const int m0 = (blockIdx.x & 63) * 256;   // n-major id: A panel stays on XCD
  const int n0 = (blockIdx.x >> 6) * 256;
  const int lq = lane >> 4, lm = lane & 15;
  const int r16 = lane >> 2, cst = lane & 3;
  const int csrc = cst ^ ((r16 >> 1) & 3);
  const int aslot = lq ^ ((lm >> 1) & 3);
  const int K = P.K;
  const int kT = K >> 6;                     // 16

  const int gA0 = (wave & 3) + ((wave >> 2) << 3);   // R0: {0..3,8..11}
  const int gB2 = ((wave >> 1) << 2) + (wave & 1);   // R2: {0,1,4,5,8,9,12,13}
  const unsigned short* baseA0 =
      P.A + (size_t)(m0 + gA0 * 16 + r16) * K + csrc * 8;
  const unsigned short* baseA1 = baseA0 + (size_t)64 * K;   // R1 = R0 + 4 granules
  const unsigned short* baseB2 =
      P.W + (size_t)(n0 + gB2 * 16 + r16) * K + csrc * 8;
  const unsigned short* baseB3 = baseB2 + (size_t)32 * K;   // R3 = R2 + 2 granules
  const int ldsA0 = gA0 * 512 + lane * 8;
  const int ldsA1 = (gA0 + 4) * 512 + lane * 8;
  const int ldsB2 = 16384 + gB2 * 512 + lane * 8;
  const int ldsB3 = 16384 + (gB2 + 2) * 512 + lane * 8;

  auto stg = [&](const unsigned short* gbase, int ldsOff, int buf, int tsrc) {
    const unsigned short* g = gbase + tsrc * 64;
    unsigned short* l = smem + buf * 32768 + ldsOff;
    gl_lds16(g, l);               // s = 0
    gl_lds16(g + 32, l + 8192);   // s = 1
  };

  const int aBase = (wave & 1) * 8;    // A read granule base
  const int bBase = (wave >> 1) * 4;   // B read granule base
  const int rdI = lm * 32 + aslot * 8;

  auto rdA = [&](int buf, int s, int gi) {
    return *(const bf16x8*)(smem + buf * 32768 + s * 8192 + (aBase + gi) * 512 + rdI);
  };
  auto rdB = [&](int buf, int s, int gi) {
    return *(const bf16x8*)(smem + buf * 32768 + 16384 + s * 8192 + (bBase + gi) * 512 + rdI);
  };

  f32x4 acc[8][4] = {};
  bf16x8 a[2][4], b0[2][2], b1[2][2];

#define VMB8() asm volatile("s_waitcnt vmcnt(8)\ns_barrier" ::: "memory")

  stg(baseA0, ldsA0, 0, 0);
  stg(baseB2, ldsB2, 0, 0);
  stg(baseB3, ldsB3, 0, 0);
  stg(baseA1, ldsA1, 0, 0);
  stg(baseA0, ldsA0, 1, min(1, kT - 1));
  stg(baseB2, ldsB2, 1, min(1, kT - 1));

  auto iterate = [&](int t, int c) {
    const int nc = c ^ 1;
    const int t1 = min(t + 1, kT - 1);
    const int t2 = min(t + 2, kT - 1);
    // ---- p0: (qm0,qn0) ----
    VMB8();
    stg(baseB3, ldsB3, nc, t1);
    #pragma unroll
    for (int s = 0; s < 2; ++s) {
      #pragma unroll
      for (int i = 0; i < 4; ++i) a[s][i] = rdA(c, s, i);
      #pragma unroll
      for (int i = 0; i < 2; ++i) b0[s][i] = rdB(c, s, i);
    }
    __builtin_amdgcn_s_setprio(1);
    #pragma unroll
    for (int s = 0; s < 2; ++s)
      #pragma unroll
      for (int mi = 0; mi < 4; ++mi)
        #pragma unroll
        for (int ni = 0; ni < 2; ++ni)
          acc[mi][ni] = __builtin_amdgcn_mfma_f32_16x16x32_bf16(
              a[s][mi], b0[s][ni], acc[mi][ni], 0, 0, 0);
    __builtin_amdgcn_s_setprio(0);
    // ---- p1: (qm0,qn1) ----
    VMB8();
    stg(baseA1, ldsA1, nc, t1);
    #pragma unroll
    for (int s = 0; s < 2; ++s)
      #pragma unroll
      for (int i = 0; i < 2; ++i) b1[s][i] = rdB(c, s, 2 + i);
    __builtin_amdgcn_s_setprio(1);
    #pragma unroll
    for (int s = 0; s < 2; ++s)
      #pragma unroll
      for (int mi = 0; mi < 4; ++mi)
        #pragma unroll
        for (int ni = 0; ni < 2; ++ni)
          acc[mi][2 + ni] = __builtin_amdgcn_mfma_f32_16x16x32_bf16(
              a[s][mi], b1[s][ni], acc[mi][2 + ni], 0, 0, 0);
    __builtin_amdgcn_s_setprio(0);
    // ---- p2: (qm1,qn0) ----
    VMB8();
    stg(baseA0, ldsA0, c, t2);
    #pragma unroll
    for (int s = 0; s < 2; ++s)
      #pragma unroll
      for (int i = 0; i < 4; ++i) a[s][i] = rdA(c, s, 4 + i);
    __builtin_amdgcn_s_setprio(1);
    #pragma unroll
    for (int s = 0; s < 2; ++s)
      #pragma unroll
      for (int mi = 0; mi < 4; ++mi)
        #pragma unroll
        for (int ni = 0; ni < 2; ++ni)
          acc[4 + mi][ni] = __builtin_amdgcn_mfma_f32_16x16x32_bf16(
              a[s][mi], b0[s][ni], acc[4 + mi][ni], 0, 0, 0);
    __builtin_amdgcn_s_setprio(0);
    // ---- p3: (qm1,qn1) ----
    VMB8();
    stg(baseB2, ldsB2, c, t2);
    __builtin_amdgcn_s_setprio(1);
    #pragma unroll
    for (int s = 0; s < 2; ++s)
      #pragma unroll
      for (int mi = 0; mi < 4; ++mi)
        #pragma unroll
        for (int ni = 0; ni < 2; ++ni)
          acc[4 + mi][2 + ni] = __builtin_amdgcn_mfma_f32_16x16x32_bf16(
              a[s][mi], b1[s][ni], acc[4 + mi][2 + ni], 0, 0, 0);
    __builtin_amdgcn_s_setprio(0);
  };

  #pragma unroll 1
  for (int t = 0; t < kT; t += 2) {
    iterate(t, 0);
    iterate(t + 1, 1);
  }
  asm volatile("s_waitcnt vmcnt(0)" ::: "memory");
#undef VMB8

  #pragma unroll
  for (int mi = 0; mi < 8; ++mi) {
    #pragma unroll
    for (int ni = 0; ni < 4; ++ni) {
      const int col = n0 + wn + ni * 16 + lm;
      #pragma unroll
      for (int r2 = 0; r2 < 4; ++r2) {
        const int row = m0 + wm + mi * 16 + lq * 4 + r2;
        ((unsigned short*)P.C)[(size_t)row * 1024 + col] =
            f2bf(acc[mi][ni][r2] + P.b0[col]);
      }
    }
  }
}

// ---------------- fused softmax + MS-deform bilinear sampling --------------
// Two-phase (R7): phase 1 = one thread per (head,point) computes softmax,
// bilinear corner weights and packed gather descriptor into bank-padded
// LDS tables; phase 2 = channel lanes gather + accumulate.
template <int NLEV>
__global__ __launch_bounds__(256) void ms_sample_fused(
    const unsigned short* __restrict__ value, const float* __restrict__ off,
    const float* __restrict__ logits, unsigned short* __restrict__ out) {
  constexpr int NPTS = NLEV * 4;
  constexpr int STR = NPTS + 1;  // LDS row pad: h-groups hit distinct banks
  __shared__ float4 wTab[16 * STR];
  __shared__ int2  iTab[16 * STR];
  const int nq = blockIdx.x;               // n*1024 + q
  const int tid = threadIdx.x;
  const int q = nq & 1023, n = nq >> 10;

  if (tid < 16 * NPTS) {
    const int h1 = tid / NPTS;             // NPTS power of 2 -> shift
    const int p1 = tid - h1 * NPTS;        // point index (l*4+p)
    float lg = logits[((size_t)nq * 16 + h1) * NPTS + p1];
    float mx = lg;
    #pragma unroll
    for (int m = 1; m < NPTS; m <<= 1) mx = fmaxf(mx, __shfl_xor(mx, m));
    const float e = __expf(lg - mx);
    float sum = e;
    #pragma unroll
    for (int m = 1; m < NPTS; m <<= 1) sum += __shfl_xor(sum, m);
    const float aw = e / sum;
    const float2 o2 =
        ((const float2*)(off + ((size_t)nq * 16 + h1) * NPTS * 2))[p1];
    const float fqx = (float)(q & 31), fqy = (float)(q >> 5);
    float xx = fqx + o2.x, yy = fqy + o2.y;
    float xf = floorf(xx), yf = floorf(yy);
    float fx = xx - xf, fy = yy - yf;
    int ix = (int)xf, iy = (int)yf;
    int ix1 = ix + 1, iy1 = iy + 1;
    float vx0 = ((unsigned)ix  < 32u) ? 1.f : 0.f;
    float vx1 = ((unsigned)ix1 < 32u) ? 1.f : 0.f;
    float vy0 = ((unsigned)iy  < 32u) ? 1.f : 0.f;
    float vy1 = ((unsigned)iy1 < 32u) ? 1.f : 0.f;
    int cx0 = min(max(ix, 0), 31), cx1 = min(max(ix1, 0), 31);
    int cy0 = min(max(iy, 0), 31), cy1 = min(max(iy1, 0), 31);
    float4 w;
    w.x = (1.f - fx) * (1.f - fy) * vx0 * vy0 * aw;
    w.y = fx * (1.f - fy) * vx1 * vy0 * aw;
    w.z = (1.f - fx) * fy * vx0 * vy1 * aw;
    w.w = fx * fy * vx1 * vy1 * aw;
    const int l = p1 >> 2;
    int2 io;
    io.x = ((n * NLEV + l) << 20) + ((cy0 * 32 + cx0) << 10);  // element off
    io.y = (cx1 - cx0) | ((cy1 - cy0) << 1);                   // dx | dy<<1
    wTab[h1 * STR + p1] = w;
    iTab[h1 * STR + p1] = io;
  }
  __syncthreads();

  const int wave = tid >> 6, lane = tid & 63;
  const int h = (wave << 2) + (lane >> 4);
  const int c = (lane & 15) << 2;          // channel base (0..60)
  const unsigned short* __restrict__ vb = value + h * 64 + c;
  float a0 = 0.f, a1 = 0.f, a2 = 0.f, a3 = 0.f;

  #pragma unroll 4
  for (int p = 0; p < NPTS; ++p) {
    const float4 w = wTab[h * STR + p];    // broadcast within 16-lane group
    const int2 io = iTab[h * STR + p];
    const unsigned short* b = vb + io.x;
    const int sx = (io.y & 1) << 10;       // +1 position = 1024 elements
    const int sy = (io.y & 2) << 14;       // +1 row = 32768 elements
    ushort4 u00 = *(const ushort4*)(b);
    ushort4 u01 = *(const ushort4*)(b + sx);
    ushort4 u10 = *(const ushort4*)(b + sy);
    ushort4 u11 = *(const ushort4*)(b + sx + sy);
    a0 += w.x * bf2f(u00.x) + w.y * bf2f(u01.x) + w.z * bf2f(u10.x) + w.w * bf2f(u11.x);
    a1 += w.x * bf2f(u00.y) + w.y * bf2f(u01.y) + w.z * bf2f(u10.y) + w.w * bf2f(u11.y);
    a2 += w.x * bf2f(u00.z) + w.y * bf2f(u01.z) + w.z * bf2f(u10.z) + w.w * bf2f(u11.z);
    a3 += w.x * bf2f(u00.w) + w.y * bf2f(u01.w) + w.z * bf2f(u10.w) + w.w * bf2f(u11.w);
  }
  ushort4 r;
  r.x = f2bf(a0); r.y = f2bf(a1); r.z = f2bf(a2); r.w = f2bf(a3);
  *(ushort4*)(out + ((size_t)nq * 16 + h) * 64 + c) = r;
}

// ---------------------------------------------------------------------------
extern "C" void kernel_launch(void* const* d_in, const int* in_sizes, int n_in,
                              void* d_out, int out_size, void* d_ws,
                              size_t ws_size, hipStream_t stream) {
  (void)in_sizes; (void)n_in; (void)out_size; (void)ws_size;
  const float* src[4] = {(const float*)d_in[0], (const float*)d_in[1],
                         (const float*)d_in[2], (const float*)d_in[3]};
  const float* qn_g = (const float*)d_in[4];
  const float* qn_b = (const float*)d_in[5];
  const float* fn_g = (const float*)d_in[6];
  const float* fn_b = (const float*)d_in[7];
  const float* n1_g = (const float*)d_in[8];
  const float* n1_b = (const float*)d_in[9];
  const float* gamma1 = (const float*)d_in[10];
  const float* gamma2 = (const float*)d_in[11];
  const float* ca_vw = (const float*)d_in[12];
  const float* ca_vb = (const float*)d_in[13];
  const float* ca_ow = (const float*)d_in[14];
  const float* ca_ob = (const float*)d_in[15];
  const float* ca_aw = (const float*)d_in[16];
  const float* ca_ab = (const float*)d_in[17];
  const float* ca_pw = (const float*)d_in[18];
  const float* ca_pb = (const float*)d_in[19];
  const float* sa_vw = (const float*)d_in[20];
  const float* sa_vb = (const float*)d_in[21];
  const float* sa_ow = (const float*)d_in[22];
  const float* sa_ob = (const float*)d_in[23];
  const float* sa_aw = (const float*)d_in[24];
  const float* sa_ab = (const float*)d_in[25];
  const float* sa_pw = (const float*)d_in[26];
  const float* sa_pb = (const float*)d_in[27];

  // ---- workspace layout ----
  char* wsp = (char*)d_ws;
  size_t off = 0;
  auto alloc = [&](size_t bytes) {
    char* r = wsp + off;
    off = (off + bytes + 255) & ~(size_t)255;
    return r;
  };
  const size_t MB = 1024 * 1024;
  unsigned short* w_ca_vw = (unsigned short*)alloc(1024 * 1024 * 2);
  unsigned short* w_ca_ow = (unsigned short*)alloc(512 * 1024 * 2);
  unsigned short* w_ca_aw = (unsigned short*)alloc(256 * 1024 * 2);
  unsigned short* w_ca_pw = (unsigned short*)alloc(1024 * 1024 * 2);
  unsigned short* w_sa_vw = (unsigned short*)alloc(1024 * 1024 * 2);
  unsigned short* w_sa_ow = (unsigned short*)alloc(128 * 1024 * 2);
  unsigned short* w_sa_aw = (unsigned short*)alloc(64 * 1024 * 2);
  unsigned short* w_sa_pw = (unsigned short*)alloc(1024 * 1024 * 2);
  (void)w_ca_aw; (void)w_sa_ow; (void)w_sa_aw;
  char* R1 = alloc(32 * MB);  // f_ln bf16 | attn f32 + attn1 bf16 + samp_sa bf16
  char* R2 = alloc(32 * MB);  // val_ca bf16 | val_sa bf16
  char* R3 = alloc(8 * MB);   // q_ln bf16 | samp_ca bf16
  char* R4 = alloc(8 * MB);   // off_ca f32 | off_sa f32 + attw_sa f32
  char* R5 = alloc(4 * MB);   // attw_ca f32 (raw logits; softmax fused)

  unsigned short* f_ln    = (unsigned short*)R1;
  float*          attn    = (float*)R1;
  unsigned short* attn1   = (unsigned short*)(R1 + 16 * MB);
  unsigned short* samp_sa = (unsigned short*)(R1 + 24 * MB);
  unsigned short* val_ca  = (unsigned short*)R2;
  unsigned short* val_sa  = (unsigned short*)R2;
  unsigned short* q_ln    = (unsigned short*)R3;
  unsigned short* samp_ca = (unsigned short*)R3;
  float*          off_ca  = (float*)R4;
  float*          off_sa  = (float*)R4;
  float*          attw_sa = (float*)(R4 + 4 * MB);
  float*          attw_ca = (float*)R5;

  // ---- 1. merged weight conversion ----
  CvtArgs ca;
  ca.src[0] = ca_vw; ca.src[1] = ca_ow; ca.src[2] = ca_aw; ca.src[3] = ca_pw;
  ca.src[4] = sa_vw; ca.src[5] = sa_ow; ca.src[6] = sa_aw; ca.src[7] = sa_pw;
  ca.dst = w_ca_vw;
  const int sizes4[8] = {262144, 131072, 65536, 262144, 262144, 32768, 16384, 262144};
  ca.off4[0] = 0;
  for (int i = 0; i < 8; ++i) ca.off4[i + 1] = ca.off4[i] + sizes4[i];
  f2bf_multi<<<ca.off4[8] / 256, 256, 0, stream>>>(ca);

  // ---- 2. LayerNorms (feat x4 + query; wave per row) ----
  ln5_wave_kernel<<<5120, 256, 0, stream>>>(src[0], src[1], src[2], src[3],
                                            fn_g, fn_b, qn_g, qn_b, f_ln, q_ln);

  auto mkP = [](const unsigned short* A, const unsigned short* W, void* C,
                const float* b0, int M, int N, int K, int tilesM) {
    GemmP p{}; p.A = A; p.W = W; p.C = C; p.b0 = b0;
    p.M = M; p.N = N; p.K = K; p.tilesM = tilesM;
    return p;
  };

  // ---- 3. CA: value GEMM (256^2 counted-vmcnt) + off/attw GEMM ----
  gemm256<<<256, 512, 0, stream>>>(
      mkP(f_ln, w_ca_vw, val_ca, ca_vb, 16384, 1024, 1024, 64));
  {
    GemmP po = mkP(q_ln, w_ca_ow, off_ca, ca_ob, 4096, 768, 1024, 64);
    po.C1 = attw_ca; po.b1 = ca_ab;
    gemm_v3<64, 128, 2><<<384, 256, 0, stream>>>(po);
  }

  // ---- 4. CA sampling + projection ----
  ms_sample_fused<4><<<4096, 256, 0, stream>>>(val_ca, off_ca, attw_ca, samp_ca);
  gemm_v3<64, 128, 0><<<512, 256, 0, stream>>>(
      mkP(samp_ca, w_ca_pw, attn, ca_pb, 4096, 1024, 1024, 64));

  // ---- 5. SA branch ----
  ln_wave_kernel<<<1024, 256, 0, stream>>>(attn, n1_g, n1_b, attn1);
  {
    GemmP p = mkP(attn1, w_sa_vw, val_sa, sa_vb, 4096, 1216, 1024, 64);
    p.C1 = off_sa; p.b1 = sa_ob; p.C2 = attw_sa; p.b2 = sa_ab;
    gemm_v3<64, 128, 3><<<640, 256, 0, stream>>>(p);
  }
  ms_sample_fused<1><<<4096, 256, 0, stream>>>(val_sa, off_sa, attw_sa, samp_sa);
  {
    GemmP p = mkP(samp_sa, w_sa_pw, d_out, sa_pb, 4096, 1024, 1024, 64);
    p.src3 = src[3]; p.g1 = gamma1; p.g2 = gamma2; p.attnp = attn;
    gemm_v3<64, 128, 4><<<512, 256, 0, stream>>>(p);
  }
}

// Round 5
// 336.388 us; speedup vs baseline: 1.0877x; 1.0455x over previous
//
#include <hip/hip_runtime.h>

// ---------------------------------------------------------------------------
// MSCrossAttnBlock on MI355X (gfx950).
// B=4, E=32, LQ=1024, D=1024, NH=16, DH=64, NP=4. All levels are 32x32.
// R9: ledger analysis (R0-R4 totals) showed the four M=4096 GEMMs cost
//     ~55us EACH in every low-TLP config (~64% of runtime); only the
//     4.75-blocks/CU config (R1 dual) ever ran at ~13us/tile. Per-iter
//     stall ~2-4kcy load latency is hidden by co-resident blocks, not by
//     pipeline depth. So: all four small GEMMs -> 64x64 tiles on the
//     race-free R5 2-phase structure (32KB LDS), grids 768/1024/1216/1024
//     = 3-4.75 bl/CU. The racy R8 3-slot vmcnt(16) path is deleted
//     (it waited 4 loads short: absmax 0.089 -> back to 0.03125).
//     f2bf + ln5 merged into one dispatch. 9 dispatches.
// ---------------------------------------------------------------------------

#define DEV __device__ __forceinline__

typedef float f32x4 __attribute__((ext_vector_type(4)));
typedef __bf16 bf16x8 __attribute__((ext_vector_type(8)));

DEV unsigned short f2bf(float f) {
  union { float f; unsigned u; } a; a.f = f;
  unsigned r = a.u + 0x7fffu + ((a.u >> 16) & 1u);
  return (unsigned short)(r >> 16);
}
DEV float bf2f(unsigned short h) {
  union { unsigned u; float f; } a; a.u = ((unsigned)h) << 16;
  return a.f;
}

// async global -> LDS, 16B per lane; LDS dest = uniform base + lane*16.
DEV void gl_lds16(const unsigned short* g, unsigned short* l) {
  __builtin_amdgcn_global_load_lds(
      (const __attribute__((address_space(1))) void*)g,
      (__attribute__((address_space(3))) void*)l, 16, 0, 0);
}

// ---------------- merged weight fp32 -> bf16 conversion --------------------
struct CvtArgs {
  const float* src[8];
  unsigned short* dst;
  int off4[9];  // prefix sums, float4 units
};

// ---------------- LayerNorm row helper (one wave, no barriers) -------------
DEV void ln_row_wave(const float* __restrict__ xr, const float* __restrict__ g,
                     const float* __restrict__ b,
                     unsigned short* __restrict__ op_row) {
  const int lane = threadIdx.x & 63;
  float4 v[4];
  float s = 0.f, s2 = 0.f;
  #pragma unroll
  for (int j = 0; j < 4; ++j) {
    v[j] = ((const float4*)xr)[lane + 64 * j];
    s  += v[j].x + v[j].y + v[j].z + v[j].w;
    s2 += v[j].x*v[j].x + v[j].y*v[j].y + v[j].z*v[j].z + v[j].w*v[j].w;
  }
  #pragma unroll
  for (int o = 32; o; o >>= 1) { s += __shfl_xor(s, o); s2 += __shfl_xor(s2, o); }
  const float mean = s * (1.f / 1024.f);
  const float rstd = rsqrtf(s2 * (1.f / 1024.f) - mean * mean + 1e-6f);
  #pragma unroll
  for (int j = 0; j < 4; ++j) {
    float4 gg = ((const float4*)g)[lane + 64 * j];
    float4 bb = ((const float4*)b)[lane + 64 * j];
    ushort4 r;
    r.x = f2bf((v[j].x - mean) * rstd * gg.x + bb.x);
    r.y = f2bf((v[j].y - mean) * rstd * gg.y + bb.y);
    r.z = f2bf((v[j].z - mean) * rstd * gg.z + bb.z);
    r.w = f2bf((v[j].w - mean) * rstd * gg.w + bb.w);
    ((ushort4*)op_row)[lane + 64 * j] = r;
  }
}

__global__ __launch_bounds__(256) void ln_wave_kernel(
    const float* __restrict__ x, const float* __restrict__ g,
    const float* __restrict__ b, unsigned short* __restrict__ out) {
  int row = blockIdx.x * 4 + (threadIdx.x >> 6);
  ln_row_wave(x + (size_t)row * 1024, g, b, out + (size_t)row * 1024);
}

// merged: blocks [0,5120) = 5 LayerNorms (feat x4 -> f_ln, query -> q_ln);
//         blocks [5120, 5120+5056) = weight f32->bf16 conversion.
__global__ __launch_bounds__(256) void cvt_ln5_kernel(
    CvtArgs a,
    const float* __restrict__ s0, const float* __restrict__ s1,
    const float* __restrict__ s2, const float* __restrict__ s3,
    const float* __restrict__ fg, const float* __restrict__ fb,
    const float* __restrict__ qg, const float* __restrict__ qb,
    unsigned short* __restrict__ f_out, unsigned short* __restrict__ q_out) {
  if (blockIdx.x < 5120) {
    int row = blockIdx.x * 4 + (threadIdx.x >> 6);  // 0..20479
    if (row < 16384) {
      int l = row >> 12, inner = row & 4095;
      const float* srcs[4] = {s0, s1, s2, s3};
      int orow = (inner >> 10) * 4096 + l * 1024 + (inner & 1023);
      ln_row_wave(srcs[l] + (size_t)inner * 1024, fg, fb,
                  f_out + (size_t)orow * 1024);
    } else {
      int inner = row - 16384;
      ln_row_wave(s3 + (size_t)inner * 1024, qg, qb,
                  q_out + (size_t)inner * 1024);
    }
  } else {
    int i = (blockIdx.x - 5120) * 256 + threadIdx.x;  // float4 index, exact
    int seg = 0;
    #pragma unroll
    for (int s = 1; s < 8; ++s) seg += (i >= a.off4[s]) ? 1 : 0;
    const float4 v = ((const float4*)a.src[seg])[i - a.off4[seg]];
    unsigned short* o = a.dst + (size_t)i * 4;
    o[0] = f2bf(v.x); o[1] = f2bf(v.y); o[2] = f2bf(v.z); o[3] = f2bf(v.w);
  }
}

// ---------------- shared GEMM param block ----------------------------------
struct GemmP {
  const unsigned short* A; const unsigned short* W;
  void* C; void* C1; void* C2;
  const float* b0; const float* b1; const float* b2;
  const float* src3; const float* g1; const float* g2; const float* attnp;
  int M, N, K, tilesM;
};

// ---------------- bf16 MFMA GEMM, R5 2-phase dbuf (race-free) --------------
// C[M,N] = A[M,K] @ W[N,K]^T (+bias). BK=64 as two 32-k sub-tiles.
// stage(t+1) issued before compute(t); __syncthreads' vmcnt(0) drain lands
// after the MFMA phase. Run at >=3 blocks/CU (64x64 tiles): per-iter load
// latency (~2-4kcy) is hidden by co-resident blocks (R9 ledger analysis).
// EPI: 0=f32, 1=bf16, 2=CA split(off512|attw256), 3=SA split(val1024 bf16|
//      off128 f32|attw64 f32), 4=final combine -> d_out.
template <int BM, int BN, int EPI>
DEV void gemm_body(const GemmP& P, int id, unsigned short* smem) {
  constexpr int WMT = BM / 2, WNT = BN / 2;
  constexpr int MF = WMT / 16, NF = WNT / 16;
  constexpr int PA = BM / 64, PB = BN / 64;    // granule passes per sub-tile
  constexpr int BUF = (BM + BN) * 64;          // elements per LDS buffer
  const int tid = threadIdx.x;
  const int wave = tid >> 6, lane = tid & 63;
  const int wm = (wave & 1) * WMT, wn = (wave >> 1) * WNT;
  const int m0 = (id % P.tilesM) * BM;
  const int n0 = (id / P.tilesM) * BN;
  const int lq = lane >> 4, lm = lane & 15;
  const int r16 = lane >> 2;                    // row within granule
  const int cst = lane & 3;                     // slot within row
  const int csrc = cst ^ ((r16 >> 1) & 3);      // global k-chunk for slot
  const int aslot = lq ^ ((lm >> 1) & 3);       // read slot for chunk lq

  f32x4 acc[MF][NF] = {};
  const int kTiles = P.K >> 6;

  const unsigned short* gA[PA];
  #pragma unroll
  for (int p = 0; p < PA; ++p) {
    int grow = m0 + (wave + 4 * p) * 16 + r16;
    gA[p] = P.A + (size_t)grow * P.K + csrc * 8;
  }
  const unsigned short* gB[PB];
  #pragma unroll
  for (int p = 0; p < PB; ++p) {
    int grow = min(n0 + (wave + 4 * p) * 16 + r16, P.N - 1);
    gB[p] = P.W + (size_t)grow * P.K + csrc * 8;
  }

  auto stage = [&](int b, int t) {
    unsigned short* bA = smem + b * BUF;
    unsigned short* bB = bA + BM * 64;
    const int k0 = t << 6;
    #pragma unroll
    for (int s = 0; s < 2; ++s) {
      #pragma unroll
      for (int p = 0; p < PA; ++p)
        gl_lds16(gA[p] + k0 + s * 32,
                 bA + s * BM * 32 + (wave + 4 * p) * 512);
      #pragma unroll
      for (int p = 0; p < PB; ++p)
        gl_lds16(gB[p] + k0 + s * 32,
                 bB + s * BN * 32 + (wave + 4 * p) * 512);
    }
  };

  stage(0, 0);
  __syncthreads();                 // vmcnt(0) drain: buf0 ready
  int cur = 0;
  #pragma unroll 1
  for (int t = 0; t < kTiles; ++t) {
    if (t + 1 < kTiles) stage(cur ^ 1, t + 1);  // async issue, no wait yet
    const unsigned short* bA = smem + cur * BUF;
    const unsigned short* bB = bA + BM * 64;
    #pragma unroll
    for (int s = 0; s < 2; ++s) {
      bf16x8 af[MF], bfr[NF];
      #pragma unroll
      for (int mi = 0; mi < MF; ++mi)
        af[mi] = *(const bf16x8*)(bA + s * BM * 32 + ((wm >> 4) + mi) * 512 + lm * 32 + aslot * 8);
      #pragma unroll
      for (int ni = 0; ni < NF; ++ni)
        bfr[ni] = *(const bf16x8*)(bB + s * BN * 32 + ((wn >> 4) + ni) * 512 + lm * 32 + aslot * 8);
      #pragma unroll
      for (int mi = 0; mi < MF; ++mi)
        #pragma unroll
        for (int ni = 0; ni < NF; ++ni)
          acc[mi][ni] = __builtin_amdgcn_mfma_f32_16x16x32_bf16(
              af[mi], bfr[ni], acc[mi][ni], 0, 0, 0);
    }
    __syncthreads();   // drains this iter's stage (after MFMA) + barrier
    cur ^= 1;
  }

  #pragma unroll
  for (int mi = 0; mi < MF; ++mi) {
    #pragma unroll
    for (int ni = 0; ni < NF; ++ni) {
      const int col = n0 + wn + ni * 16 + lm;
      #pragma unroll
      for (int r2 = 0; r2 < 4; ++r2) {
        const int row = m0 + wm + mi * 16 + lq * 4 + r2;
        float v = acc[mi][ni][r2];
        if constexpr (EPI == 0) {
          ((float*)P.C)[(size_t)row * 1024 + col] = v + P.b0[col];
        } else if constexpr (EPI == 1) {
          ((unsigned short*)P.C)[(size_t)row * 1024 + col] = f2bf(v + P.b0[col]);
        } else if constexpr (EPI == 2) {
          if (col < 512)
            ((float*)P.C)[(size_t)row * 512 + col] = v + P.b0[col];
          else
            ((float*)P.C1)[(size_t)row * 256 + col - 512] = v + P.b1[col - 512];
        } else if constexpr (EPI == 3) {
          if (col < 1024)
            ((unsigned short*)P.C)[(size_t)row * 1024 + col] = f2bf(v + P.b0[col]);
          else if (col < 1152)
            ((float*)P.C1)[(size_t)row * 128 + col - 1024] = v + P.b1[col - 1024];
          else if (col < 1216)
            ((float*)P.C2)[(size_t)row * 64 + col - 1152] = v + P.b2[col - 1152];
        } else {  // EPI == 4: out = src3 + g1*(attn + g2*(v+b))
          size_t i = (size_t)row * 1024 + col;
          float vv = v + P.b0[col];
          ((float*)P.C)[i] = P.src3[i] + P.g1[col] * (P.attnp[i] + P.g2[col] * vv);
        }
      }
    }
  }
}

template <int BM, int BN, int EPI>
__global__ __launch_bounds__(256) void gemm_v3(GemmP P) {
  extern __shared__ __align__(16) unsigned short smem[];
  gemm_body<BM, BN, EPI>(P, blockIdx.x, smem);
}

// ---------------- 256^2 8-wave 4-phase counted-vmcnt GEMM (CA value) -------
// See R6 comment block: T3+T4+T5, region schedule from quadrant death
// analysis, vmcnt(8) uniform (2 loads/stage, verified ledger), epilogue
// staging clamped to kT-1. absmax-verified (R2/R3: 0.03125).
__global__ __launch_bounds__(512, 2) void gemm256(GemmP P) {
  __shared__ __align__(16) unsigned short smem[65536];  // 128KB
  const int tid = threadIdx.x;
  const int wave = tid >> 6, lane = tid & 63;
  const int wm = (wave & 1) * 128, wn = (wave >> 1) * 64;
  const int m0 = (blockIdx.x & 63) * 256;   // n-major id: A panel stays on XCD
  const int n0 = (blockIdx.x >> 6) * 256;
  const int lq = lane >> 4, lm = lane & 15;
  const int r16 = lane >> 2, cst = lane & 3;
  const int csrc = cst ^ ((r16 >> 1) & 3);
  const int aslot = lq ^ ((lm >> 1) & 3);
  const int K = P.K;
  const int kT = K >> 6;                     // 16

  const int gA0 = (wave & 3) + ((wave >> 2) << 3);   // R0: {0..3,8..11}
  const int gB2 = ((wave >> 1) << 2) + (wave & 1);   // R2: {0,1,4,5,8,9,12,13}
  const unsigned short* baseA0 =
      P.A + (size_t)(m0 + gA0 * 16 + r16) * K + csrc * 8;
  const unsigned short* baseA1 = baseA0 + (size_t)64 * K;   // R1 = R0 + 4 granules
  const unsigned short* baseB2 =
      P.W + (size_t)(n0 + gB2 * 16 + r16) * K + csrc * 8;
  const unsigned short* baseB3 = baseB2 + (size_t)32 * K;   // R3 = R2 + 2 granules
  const int ldsA0 = gA0 * 512 + lane * 8;
  const int ldsA1 = (gA0 + 4) * 512 + lane * 8;
  const int ldsB2 = 16384 + gB2 * 512 + lane * 8;
  const int ldsB3 = 16384 + (gB2 + 2) * 512 + lane * 8;

  auto stg = [&](const unsigned short* gbase, int ldsOff, int buf, int tsrc) {
    const unsigned short* g = gbase + tsrc * 64;
    unsigned short* l = smem + buf * 32768 + ldsOff;
    gl_lds16(g, l);               // s = 0
    gl_lds16(g + 32, l + 8192);   // s = 1
  };

  const int aBase = (wave & 1) * 8;    // A read granule base
  const int bBase = (wave >> 1) * 4;   // B read granule base
  const int rdI = lm * 32 + aslot * 8;

  auto rdA = [&](int buf, int s, int gi) {
    return *(const bf16x8*)(smem + buf * 32768 + s * 8192 + (aBase + gi) * 512 + rdI);
  };
  auto rdB = [&](int buf, int s, int gi) {
    return *(const bf16x8*)(smem + buf * 32768 + 16384 + s * 8192 + (bBase + gi) * 512 + rdI);
  };

  f32x4 acc[8][4] = {};
  bf16x8 a[2][4], b0[2][2], b1[2][2];

#define VMB8() asm volatile("s_waitcnt vmcnt(8)\ns_barrier" ::: "memory")

  stg(baseA0, ldsA0, 0, 0);
  stg(baseB2, ldsB2, 0, 0);
  stg(baseB3, ldsB3, 0, 0);
  stg(baseA1, ldsA1, 0, 0);
  stg(baseA0, ldsA0, 1, min(1, kT - 1));
  stg(baseB2, ldsB2, 1, min(1, kT - 1));

  auto iterate = [&](int t, int c) {
    const int nc = c ^ 1;
    const int t1 = min(t + 1, kT - 1);
    const int t2 = min(t + 2, kT - 1);
    // ---- p0: (qm0,qn0) ----
    VMB8();
    stg(baseB3, ldsB3, nc, t1);
    #pragma unroll
    for (int s = 0; s < 2; ++s) {
      #pragma unroll
      for (int i = 0; i < 4; ++i) a[s][i] = rdA(c, s, i);
      #pragma unroll
      for (int i = 0; i < 2; ++i) b0[s][i] = rdB(c, s, i);
    }
    __builtin_amdgcn_s_setprio(1);
    #pragma unroll
    for (int s = 0; s < 2; ++s)
      #pragma unroll
      for (int mi = 0; mi < 4; ++mi)
        #pragma unroll
        for (int ni = 0; ni < 2; ++ni)
          acc[mi][ni] = __builtin_amdgcn_mfma_f32_16x16x32_bf16(
              a[s][mi], b0[s][ni], acc[mi][ni], 0, 0, 0);
    __builtin_amdgcn_s_setprio(0);
    // ---- p1: (qm0,qn1) ----
    VMB8();
    stg(baseA1, ldsA1, nc, t1);
    #pragma unroll
    for (int s = 0; s < 2; ++s)
      #pragma unroll
      for (int i = 0; i < 2; ++i) b1[s][i] = rdB(c, s, 2 + i);
    __builtin_amdgcn_s_setprio(1);
    #pragma unroll
    for (int s = 0; s < 2; ++s)
      #pragma unroll
      for (int mi = 0; mi < 4; ++mi)
        #pragma unroll
        for (int ni = 0; ni < 2; ++ni)
          acc[mi][2 + ni] = __builtin_amdgcn_mfma_f32_16x16x32_bf16(
              a[s][mi], b1[s][ni], acc[mi][2 + ni], 0, 0, 0);
    __builtin_amdgcn_s_setprio(0);
    // ---- p2: (qm1,qn0) ----
    VMB8();
    stg(baseA0, ldsA0, c, t2);
    #pragma unroll
    for (int s = 0; s < 2; ++s)
      #pragma unroll
      for (int i = 0; i < 4; ++i) a[s][i] = rdA(c, s, 4 + i);
    __builtin_amdgcn_s_setprio(1);
    #pragma unroll
    for (int s = 0; s < 2; ++s)
      #pragma unroll
      for (int mi = 0; mi < 4; ++mi)
        #pragma unroll
        for (int ni = 0; ni < 2; ++ni)
          acc[4 + mi][ni] = __builtin_amdgcn_mfma_f32_16x16x32_bf16(
              a[s][mi], b0[s][ni], acc[4 + mi][ni], 0, 0, 0);
    __builtin_amdgcn_s_setprio(0);
    // ---- p3: (qm1,qn1) ----
    VMB8();
    stg(baseB2, ldsB2, c, t2);
    __builtin_amdgcn_s_setprio(1);
    #pragma unroll
    for (int s = 0; s < 2; ++s)
      #pragma unroll
      for (int mi = 0; mi < 4; ++mi)
        #pragma unroll
        for (int ni = 0; ni < 2; ++ni)
          acc[4 + mi][2 + ni] = __builtin_amdgcn_mfma_f32_16x16x32_bf16(
              a[s][mi], b1[s][ni], acc[4 + mi][2 + ni], 0, 0, 0);
    __builtin_amdgcn_s_setprio(0);
  };

  #pragma unroll 1
  for (int t = 0; t < kT; t += 2) {
    iterate(t, 0);
    iterate(t + 1, 1);
  }
  asm volatile("s_waitcnt vmcnt(0)" ::: "memory");
#undef VMB8

  #pragma unroll
  for (int mi = 0; mi < 8; ++mi) {
    #pragma unroll
    for (int ni = 0; ni < 4; ++ni) {
      const int col = n0 + wn + ni * 16 + lm;
      #pragma unroll
      for (int r2 = 0; r2 < 4; ++r2) {
        const int row = m0 + wm + mi * 16 + lq * 4 + r2;
        ((unsigned short*)P.C)[(size_t)row * 1024 + col] =
            f2bf(acc[mi][ni][r2] + P.b0[col]);
      }
    }
  }
}

// ---------------- fused softmax + MS-deform bilinear sampling --------------
// Two-phase (R7): phase 1 = one thread per (head,point) computes softmax,
// bilinear corner weights and packed gather descriptor into bank-padded
// LDS tables; phase 2 = channel lanes gather + accumulate.
template <int NLEV>
__global__ __launch_bounds__(256) void ms_sample_fused(
    const unsigned short* __restrict__ value, const float* __restrict__ off,
    const float* __restrict__ logits, unsigned short* __restrict__ out) {
  constexpr int NPTS = NLEV * 4;
  constexpr int STR = NPTS + 1;  // LDS row pad: h-groups hit distinct banks
  __shared__ float4 wTab[16 * STR];
  __shared__ int2  iTab[16 * STR];
  const int nq = blockIdx.x;               // n*1024 + q
  const int tid = threadIdx.x;
  const int q = nq & 1023, n = nq >> 10;

  if (tid < 16 * NPTS) {
    const int h1 = tid / NPTS;
    const int p1 = tid - h1 * NPTS;        // point index (l*4+p)
    float lg = logits[((size_t)nq * 16 + h1) * NPTS + p1];
    float mx = lg;
    #pragma unroll
    for (int m = 1; m < NPTS; m <<= 1) mx = fmaxf(mx, __shfl_xor(mx, m));
    const float e = __expf(lg - mx);
    float sum = e;
    #pragma unroll
    for (int m = 1; m < NPTS; m <<= 1) sum += __shfl_xor(sum, m);
    const float aw = e / sum;
    const float2 o2 =
        ((const float2*)(off + ((size_t)nq * 16 + h1) * NPTS * 2))[p1];
    const float fqx = (float)(q & 31), fqy = (float)(q >> 5);
    float xx = fqx + o2.x, yy = fqy + o2.y;
    float xf = floorf(xx), yf = floorf(yy);
    float fx = xx - xf, fy = yy - yf;
    int ix = (int)xf, iy = (int)yf;
    int ix1 = ix + 1, iy1 = iy + 1;
    float vx0 = ((unsigned)ix  < 32u) ? 1.f : 0.f;
    float vx1 = ((unsigned)ix1 < 32u) ? 1.f : 0.f;
    float vy0 = ((unsigned)iy  < 32u) ? 1.f : 0.f;
    float vy1 = ((unsigned)iy1 < 32u) ? 1.f : 0.f;
    int cx0 = min(max(ix, 0), 31), cx1 = min(max(ix1, 0), 31);
    int cy0 = min(max(iy, 0), 31), cy1 = min(max(iy1, 0), 31);
    float4 w;
    w.x = (1.f - fx) * (1.f - fy) * vx0 * vy0 * aw;
    w.y = fx * (1.f - fy) * vx1 * vy0 * aw;
    w.z = (1.f - fx) * fy * vx0 * vy1 * aw;
    w.w = fx * fy * vx1 * vy1 * aw;
    const int l = p1 >> 2;
    int2 io;
    io.x = ((n * NLEV + l) << 20) + ((cy0 * 32 + cx0) << 10);  // element off
    io.y = (cx1 - cx0) | ((cy1 - cy0) << 1);                   // dx | dy<<1
    wTab[h1 * STR + p1] = w;
    iTab[h1 * STR + p1] = io;
  }
  __syncthreads();

  const int wave = tid >> 6, lane = tid & 63;
  const int h = (wave << 2) + (lane >> 4);
  const int c = (lane & 15) << 2;          // channel base (0..60)
  const unsigned short* __restrict__ vb = value + h * 64 + c;
  float a0 = 0.f, a1 = 0.f, a2 = 0.f, a3 = 0.f;

  #pragma unroll 4
  for (int p = 0; p < NPTS; ++p) {
    const float4 w = wTab[h * STR + p];    // broadcast within 16-lane group
    const int2 io = iTab[h * STR + p];
    const unsigned short* b = vb + io.x;
    const int sx = (io.y & 1) << 10;       // +1 position = 1024 elements
    const int sy = (io.y & 2) << 14;       // +1 row = 32768 elements
    ushort4 u00 = *(const ushort4*)(b);
    ushort4 u01 = *(const ushort4*)(b + sx);
    ushort4 u10 = *(const ushort4*)(b + sy);
    ushort4 u11 = *(const ushort4*)(b + sx + sy);
    a0 += w.x * bf2f(u00.x) + w.y * bf2f(u01.x) + w.z * bf2f(u10.x) + w.w * bf2f(u11.x);
    a1 += w.x * bf2f(u00.y) + w.y * bf2f(u01.y) + w.z * bf2f(u10.y) + w.w * bf2f(u11.y);
    a2 += w.x * bf2f(u00.z) + w.y * bf2f(u01.z) + w.z * bf2f(u10.z) + w.w * bf2f(u11.z);
    a3 += w.x * bf2f(u00.w) + w.y * bf2f(u01.w) + w.z * bf2f(u10.w) + w.w * bf2f(u11.w);
  }
  ushort4 r;
  r.x = f2bf(a0); r.y = f2bf(a1); r.z = f2bf(a2); r.w = f2bf(a3);
  *(ushort4*)(out + ((size_t)nq * 16 + h) * 64 + c) = r;
}

// ---------------------------------------------------------------------------
extern "C" void kernel_launch(void* const* d_in, const int* in_sizes, int n_in,
                              void* d_out, int out_size, void* d_ws,
                              size_t ws_size, hipStream_t stream) {
  (void)in_sizes; (void)n_in; (void)out_size; (void)ws_size;
  const float* src[4] = {(const float*)d_in[0], (const float*)d_in[1],
                         (const float*)d_in[2], (const float*)d_in[3]};
  const float* qn_g = (const float*)d_in[4];
  const float* qn_b = (const float*)d_in[5];
  const float* fn_g = (const float*)d_in[6];
  const float* fn_b = (const float*)d_in[7];
  const float* n1_g = (const float*)d_in[8];
  const float* n1_b = (const float*)d_in[9];
  const float* gamma1 = (const float*)d_in[10];
  const float* gamma2 = (const float*)d_in[11];
  const float* ca_vw = (const float*)d_in[12];
  const float* ca_vb = (const float*)d_in[13];
  const float* ca_ow = (const float*)d_in[14];
  const float* ca_ob = (const float*)d_in[15];
  const float* ca_aw = (const float*)d_in[16];
  const float* ca_ab = (const float*)d_in[17];
  const float* ca_pw = (const float*)d_in[18];
  const float* ca_pb = (const float*)d_in[19];
  const float* sa_vw = (const float*)d_in[20];
  const float* sa_vb = (const float*)d_in[21];
  const float* sa_ow = (const float*)d_in[22];
  const float* sa_ob = (const float*)d_in[23];
  const float* sa_aw = (const float*)d_in[24];
  const float* sa_ab = (const float*)d_in[25];
  const float* sa_pw = (const float*)d_in[26];
  const float* sa_pb = (const float*)d_in[27];

  // ---- workspace layout ----
  char* wsp = (char*)d_ws;
  size_t off = 0;
  auto alloc = [&](size_t bytes) {
    char* r = wsp + off;
    off = (off + bytes + 255) & ~(size_t)255;
    return r;
  };
  const size_t MB = 1024 * 1024;
  unsigned short* w_ca_vw = (unsigned short*)alloc(1024 * 1024 * 2);
  unsigned short* w_ca_ow = (unsigned short*)alloc(512 * 1024 * 2);
  unsigned short* w_ca_aw = (unsigned short*)alloc(256 * 1024 * 2);
  unsigned short* w_ca_pw = (unsigned short*)alloc(1024 * 1024 * 2);
  unsigned short* w_sa_vw = (unsigned short*)alloc(1024 * 1024 * 2);
  unsigned short* w_sa_ow = (unsigned short*)alloc(128 * 1024 * 2);
  unsigned short* w_sa_aw = (unsigned short*)alloc(64 * 1024 * 2);
  unsigned short* w_sa_pw = (unsigned short*)alloc(1024 * 1024 * 2);
  (void)w_ca_aw; (void)w_sa_ow; (void)w_sa_aw;
  char* R1 = alloc(32 * MB);  // f_ln bf16 | attn f32 + attn1 bf16 + samp_sa bf16
  char* R2 = alloc(32 * MB);  // val_ca bf16 | val_sa bf16
  char* R3 = alloc(8 * MB);   // q_ln bf16 | samp_ca bf16
  char* R4 = alloc(8 * MB);   // off_ca f32 | off_sa f32 + attw_sa f32
  char* R5 = alloc(4 * MB);   // attw_ca f32 (raw logits; softmax fused)

  unsigned short* f_ln    = (unsigned short*)R1;
  float*          attn    = (float*)R1;
  unsigned short* attn1   = (unsigned short*)(R1 + 16 * MB);
  unsigned short* samp_sa = (unsigned short*)(R1 + 24 * MB);
  unsigned short* val_ca  = (unsigned short*)R2;
  unsigned short* val_sa  = (unsigned short*)R2;
  unsigned short* q_ln    = (unsigned short*)R3;
  unsigned short* samp_ca = (unsigned short*)R3;
  float*          off_ca  = (float*)R4;
  float*          off_sa  = (float*)R4;
  float*          attw_sa = (float*)(R4 + 4 * MB);
  float*          attw_ca = (float*)R5;

  // ---- 1. merged weight conversion + 5 LayerNorms (one dispatch) ----
  CvtArgs ca;
  ca.src[0] = ca_vw; ca.src[1] = ca_ow; ca.src[2] = ca_aw; ca.src[3] = ca_pw;
  ca.src[4] = sa_vw; ca.src[5] = sa_ow; ca.src[6] = sa_aw; ca.src[7] = sa_pw;
  ca.dst = w_ca_vw;
  const int sizes4[8] = {262144, 131072, 65536, 262144, 262144, 32768, 16384, 262144};
  ca.off4[0] = 0;
  for (int i = 0; i < 8; ++i) ca.off4[i + 1] = ca.off4[i] + sizes4[i];
  cvt_ln5_kernel<<<5120 + ca.off4[8] / 256, 256, 0, stream>>>(
      ca, src[0], src[1], src[2], src[3], fn_g, fn_b, qn_g, qn_b, f_ln, q_ln);

  auto mkP = [](const unsigned short* A, const unsigned short* W, void* C,
                const float* b0, int M, int N, int K, int tilesM) {
    GemmP p{}; p.A = A; p.W = W; p.C = C; p.b0 = b0;
    p.M = M; p.N = N; p.K = K; p.tilesM = tilesM;
    return p;
  };

  constexpr int LDS_6464 = 2 * (64 + 64) * 64 * 2;  // 32768

  // ---- 2. CA: value GEMM (256^2 counted-vmcnt) + off/attw GEMM ----
  gemm256<<<256, 512, 0, stream>>>(
      mkP(f_ln, w_ca_vw, val_ca, ca_vb, 16384, 1024, 1024, 64));
  {
    GemmP po = mkP(q_ln, w_ca_ow, off_ca, ca_ob, 4096, 768, 1024, 64);
    po.C1 = attw_ca; po.b1 = ca_ab;
    gemm_v3<64, 64, 2><<<768, 256, LDS_6464, stream>>>(po);
  }

  // ---- 3. CA sampling + projection ----
  ms_sample_fused<4><<<4096, 256, 0, stream>>>(val_ca, off_ca, attw_ca, samp_ca);
  gemm_v3<64, 64, 0><<<1024, 256, LDS_6464, stream>>>(
      mkP(samp_ca, w_ca_pw, attn, ca_pb, 4096, 1024, 1024, 64));

  // ---- 4. SA branch ----
  ln_wave_kernel<<<1024, 256, 0, stream>>>(attn, n1_g, n1_b, attn1);
  {
    GemmP p = mkP(attn1, w_sa_vw, val_sa, sa_vb, 4096, 1216, 1024, 64);
    p.C1 = off_sa; p.b1 = sa_ob; p.C2 = attw_sa; p.b2 = sa_ab;
    gemm_v3<64, 64, 3><<<1216, 256, LDS_6464, stream>>>(p);
  }
  ms_sample_fused<1><<<4096, 256, 0, stream>>>(val_sa, off_sa, attw_sa, samp_sa);
  {
    GemmP p = mkP(samp_sa, w_sa_pw, d_out, sa_pb, 4096, 1024, 1024, 64);
    p.src3 = src[3]; p.g1 = gamma1; p.g2 = gamma2; p.attnp = attn;
    gemm_v3<64, 64, 4><<<1024, 256, LDS_6464, stream>>>(p);
  }
}